// Round 1
// 254.503 us; speedup vs baseline: 1.0321x; 1.0321x over previous
//
#include <hip/hip_runtime.h>
#include <hip/hip_bf16.h>

typedef __attribute__((ext_vector_type(8))) short s16x8;
typedef __attribute__((ext_vector_type(16))) float f32x16;

#define MOD_SCALE 0.014731391274719739f  // 1/sqrt(512*9)

__device__ __forceinline__ void gload_lds16(const void* g, void* l) {
    __builtin_amdgcn_global_load_lds(
        (const __attribute__((address_space(1))) unsigned int*)g,
        (__attribute__((address_space(3))) unsigned int*)l, 16, 0, 0);
}

// Full drain + barrier: used only at cb boundaries (X restage) and prologue.
__device__ __forceinline__ void sync_drain() {
    __builtin_amdgcn_s_waitcnt(0);
    __syncthreads();
}

// Counted wait (T4): at the end of tap g the outstanding VMEM ops are, in
// issue order, W(g+1) [2 loads, issued one full tap earlier] then W(g+2)
// [2 loads, issued at the top of this tap]. vmcnt(2) retires exactly W(g+1)
// (vmcnt retires in order), leaving W(g+2) in flight across the barrier.
// "memory" clobber keeps all ds/global ops (incl. loop-invariant epilogue
// loads) from crossing; sched_barrier(0) pins the raw s_barrier (rule #18).
__device__ __forceinline__ void wait2_barrier() {
    asm volatile("s_waitcnt vmcnt(2)" ::: "memory");
    __builtin_amdgcn_sched_barrier(0);
    __builtin_amdgcn_s_barrier();
    __builtin_amdgcn_sched_barrier(0);
}

// ---------------------------------------------------------------------------
// Fused prep kernel (unchanged, proven): blockIdx ranges
//   [0,520) border zero | [520,2568) xprep | [2568,3592) wprep | [3592,4104) demod
// ---------------------------------------------------------------------------
__global__ __launch_bounds__(256) void k_prep(const float* __restrict__ x,
                                              const float* __restrict__ style,
                                              const float* __restrict__ weight,
                                              __hip_bfloat16* __restrict__ xs,
                                              __hip_bfloat16* __restrict__ wb,
                                              float* __restrict__ dem) {
    __shared__ __align__(16) char sm[16896];
    const int t = threadIdx.x;
    const int bid = blockIdx.x;

    if (bid < 520) {
        const int idx = bid * 256 + t;
        const int b = idx / 16640;
        const int r2 = idx - b * 16640;
        const int pair = r2 >> 6;
        const int ciq = r2 & 63;
        int pr, pc;
        if (pair < 66)       { pr = 0;          pc = pair; }
        else if (pair < 132) { pr = 65;         pc = pair - 66; }
        else if (pair < 196) { pr = pair - 131; pc = 0; }
        else                 { pr = pair - 195; pc = 65; }
        uint4* d = (uint4*)(xs + (((size_t)b * 66 + pr) * 66 + pc) * 512) + ciq;
        *d = make_uint4(0u, 0u, 0u, 0u);
    } else if (bid < 2568) {
        const int r = bid - 520;
        const int cig = r & 3, h = (r >> 2) & 63, b = r >> 8;
        const int ci0 = cig * 128;
        __hip_bfloat16 (*tile)[130] = (__hip_bfloat16(*)[130])sm;
        const int wl = t & 63, cl4 = t >> 6;
        for (int rr = 0; rr < 32; ++rr) {
            int c = rr * 4 + cl4;
            float v = x[(((size_t)b * 512 + ci0 + c) * 64 + h) * 64 + wl];
            float s = style[b * 512 + ci0 + c];
            tile[wl][c] = __float2bfloat16(v * s * MOD_SCALE);
        }
        __syncthreads();
        const int w4 = t >> 6;
        const int cp = (t & 63) * 2;
        for (int rr = 0; rr < 16; ++rr) {
            int w = rr * 4 + w4;
            unsigned v = *(const unsigned*)(&tile[w][cp]);
            *(unsigned*)(&xs[(((size_t)b * 66 + h + 1) * 66 + (w + 1)) * 512 +
                             ci0 + cp]) = v;
        }
    } else if (bid < 3592) {
        const int r = bid - 2568;
        float* lds = (float*)sm;
        const int p0 = r * 256;
        const float* src = weight + (size_t)p0 * 9;
#pragma unroll
        for (int k = 0; k < 9; ++k) lds[k * 256 + t] = src[k * 256 + t];
        __syncthreads();
#pragma unroll
        for (int tap = 0; tap < 9; ++tap)
            wb[(size_t)tap * 262144 + p0 + t] = __float2bfloat16(lds[t * 9 + tap]);
    } else {
        const int co = bid - 3592;
        float* s2 = (float*)sm;
        for (int i = t; i < 4096; i += 256) { float v = style[i]; s2[i] = v * v; }
        __syncthreads();
        const float4* wp = (const float4*)(weight + (size_t)co * 4608);
        float acc[8] = {0.f, 0.f, 0.f, 0.f, 0.f, 0.f, 0.f, 0.f};
        for (int j = t; j < 1152; j += 256) {
            float4 v = wp[j];
            float w2[4] = {v.x * v.x, v.y * v.y, v.z * v.z, v.w * v.w};
            int base = j * 4;
#pragma unroll
            for (int e = 0; e < 4; ++e) {
                int ci = (base + e) / 9;
                float ww = w2[e];
#pragma unroll
                for (int bb = 0; bb < 8; ++bb) acc[bb] += ww * s2[bb * 512 + ci];
            }
        }
#pragma unroll
        for (int bb = 0; bb < 8; ++bb)
            for (int off = 32; off > 0; off >>= 1)
                acc[bb] += __shfl_down(acc[bb], off);
        float* red = (float*)(sm + 16384);
        const int wv = t >> 6, lane = t & 63;
        if (lane == 0) {
#pragma unroll
            for (int bb = 0; bb < 8; ++bb) red[wv * 8 + bb] = acc[bb];
        }
        __syncthreads();
        if (t < 8) {
            float s = red[t] + red[8 + t] + red[16 + t] + red[24 + t];
            const float S2 = MOD_SCALE * MOD_SCALE;
            dem[t * 512 + co] = rsqrtf(S2 * s + 1e-8f);
        }
    }
}

// ---------------------------------------------------------------------------
// Conv: implicit GEMM, 32x32x16 MFMA. Block 128co x 256sp (4 rows x 64 w),
// 4 waves (wm = co half, wn = row pair), wave tile 64co x 128sp (2x4 frags).
// R7 change vs R6: W prefetch is now 2-DEEP with a TRIPLE buffer and counted
// vmcnt(2) waits at the 8 intra-cb tap boundaries (T4: never drain vmcnt to 0
// in the main loop). Since 9 % 3 == 0, buffer index = tap % 3 is a
// compile-time constant under the unroll. The X path is UNTOUCHED (single
// buffer, full-drain pair at cb boundaries — R5's race came from X prefetch;
// we do not touch X). At cb==15 taps 7/8 issue harmless in-bounds dummy
// prefetches (cb15 tap0/tap1 reload into bufs 0/1, never read) so the
// per-wave vmcnt count stays uniform; the tap-8 sync_drain retires them.
// Rotation swizzle: LDS slot s of entry e holds global chunk (s-(e>>2))&3;
// readers use slot (c+(e>>2))&3 -> b128 reads spread 8 dwords/bank.
// LDS 49,920 B -> still exactly 2 blocks/CU at grid 512.
// ---------------------------------------------------------------------------
__global__ __launch_bounds__(256, 2) void k_conv(
    const __hip_bfloat16* __restrict__ xs,   // [8][66][66][512] padded
    const __hip_bfloat16* __restrict__ wb,   // [9][512][512] tap-major
    const float* __restrict__ demod,
    const float* __restrict__ noise,
    const float* __restrict__ bias,
    const float* __restrict__ nstr,
    float* __restrict__ out) {
    __shared__ __align__(16) char Xl[25344];     // 396 entries x 64 B
    __shared__ __align__(16) char Wl[3][8192];   // 128 co x 64 B, triple buf

    const int t = threadIdx.x;
    const int bi = blockIdx.x;
    const int spat = bi & 127;            // same spat -> same bi%8 -> same XCD
    const int b = spat >> 4;
    const int h0 = (spat & 15) << 2;
    const int co0 = (bi >> 7) << 7;
    const int lane = t & 63;
    const int wv = t >> 6;
    const int wm = wv & 1, wn = wv >> 1;
    const int el = lane & 31;
    const int hk = lane >> 5;

    f32x16 acc[2][4];
#pragma unroll
    for (int i = 0; i < 2; ++i)
#pragma unroll
        for (int j = 0; j < 4; ++j)
#pragma unroll
            for (int k = 0; k < 16; ++k) acc[i][j][k] = 0.f;

    // ---- staging source pointers (rotation-swizzled) ----
    const char* xsb = (const char*)xs + (size_t)b * 66 * 66 * 1024;
    const char* xsrc[7];
#pragma unroll
    for (int i = 0; i < 6; ++i) {
        int g = i * 256 + t;
        int e = g >> 2, s = g & 3;
        int gc = (s - (e >> 2)) & 3;
        int row = e / 66, col = e - row * 66;
        xsrc[i] = xsb + (size_t)((h0 + row) * 66 + col) * 1024 + gc * 16;
    }
    {   // tail entries 384..395 (threads 0..47 only use this)
        int g = 1536 + t;
        int e = g >> 2, s = g & 3;
        int gc = (s - (e >> 2)) & 3;
        int row = e / 66, col = e - row * 66;
        xsrc[6] = xsb + (size_t)((h0 + row) * 66 + col) * 1024 + gc * 16;
    }
    const char* wsrc[2];
#pragma unroll
    for (int i = 0; i < 2; ++i) {
        int g = i * 256 + t;
        int e = g >> 2, s = g & 3;
        int gc = (s - (e >> 2)) & 3;
        wsrc[i] = (const char*)wb + (size_t)(co0 + e) * 1024 + gc * 16;
    }
    const int wvoff = wv << 10;

    // ---- prologue: X(cb=0), W(step0)->buf0, W(step1)->buf1, full drain ----
#pragma unroll
    for (int i = 0; i < 6; ++i) gload_lds16(xsrc[i], Xl + i * 4096 + wvoff);
    if (t < 48) gload_lds16(xsrc[6], Xl + 24576);
#pragma unroll
    for (int i = 0; i < 2; ++i)
        gload_lds16(wsrc[i], Wl[0] + i * 4096 + wvoff);
#pragma unroll
    for (int i = 0; i < 2; ++i)
        gload_lds16(wsrc[i] + 524288, Wl[1] + i * 4096 + wvoff);
    sync_drain();

    int cboff = 0;
    for (int cb = 0; cb < 16; ++cb, cboff += 64) {
        // cb==15: dummy prefetch target (reload cb15 tap0/tap1; never read)
        const int ncboff = (cb < 15) ? cboff + 64 : cboff;
#pragma unroll
        for (int tap = 0; tap < 9; ++tap) {
            // ---- 2-deep W prefetch: issue step g+2 ----
            {
                char* Wn;
                size_t woff;
                if (tap < 7) {            // same cb, tap+2
                    Wn = Wl[(tap + 2) % 3];
                    woff = (size_t)(tap + 2) * 524288 + cboff;
                } else if (tap == 7) {    // next cb, tap 0
                    Wn = Wl[0];
                    woff = (size_t)ncboff;
                } else {                  // tap 8: next cb, tap 1
                    Wn = Wl[1];
                    woff = 524288 + (size_t)ncboff;
                }
                Wn += wvoff;
#pragma unroll
                for (int i = 0; i < 2; ++i)
                    gload_lds16(wsrc[i] + woff, Wn + i * 4096);
            }
            // ---- compute tap from Wl[tap % 3] ----
            const int dh = tap / 3, dw = tap % 3;
            const char* Wb = Wl[tap % 3];
#pragma unroll
            for (int ks = 0; ks < 2; ++ks) {
                const int c = 2 * ks + hk;
                s16x8 af[2], bfr[4];
#pragma unroll
                for (int mi = 0; mi < 2; ++mi) {
                    int e = wm * 64 + mi * 32 + el;
                    af[mi] = *(const s16x8*)(Wb + e * 64 +
                                             (((c + (e >> 2)) & 3) << 4));
                }
#pragma unroll
                for (int ni = 0; ni < 4; ++ni) {
                    int e = (2 * wn + (ni >> 1) + dh) * 66 + dw +
                            (ni & 1) * 32 + el;
                    bfr[ni] = *(const s16x8*)(Xl + e * 64 +
                                              (((c + (e >> 2)) & 3) << 4));
                }
#pragma unroll
                for (int mi = 0; mi < 2; ++mi)
#pragma unroll
                    for (int ni = 0; ni < 4; ++ni)
                        acc[mi][ni] = __builtin_amdgcn_mfma_f32_32x32x16_bf16(
                            af[mi], bfr[ni], acc[mi][ni], 0, 0, 0);
            }
            // ---- boundary: counted wait intra-cb, full drain at cb end ----
            if (tap < 8) wait2_barrier();
            else         sync_drain();
        }
        // ---- restage X (single buffer, between its own barrier pair) ----
        if (cb < 15) {
#pragma unroll
            for (int i = 0; i < 6; ++i)
                gload_lds16(xsrc[i] + cboff + 64, Xl + i * 4096 + wvoff);
            if (t < 48) gload_lds16(xsrc[6] + cboff + 64, Xl + 24576);
            sync_drain();
        }
    }

    // ---- epilogue: *demod + noise*strength + bias, leaky_relu(0.2)*sqrt(2) ----
    const float nsv = nstr[0];
    const float LR = 1.4142135623730951f;
#pragma unroll
    for (int mi = 0; mi < 2; ++mi) {
        float dm[16], bs[16];
#pragma unroll
        for (int rg = 0; rg < 16; ++rg) {
            int co = co0 + wm * 64 + mi * 32 + (rg & 3) + 8 * (rg >> 2) + 4 * hk;
            dm[rg] = demod[b * 512 + co];
            bs[rg] = bias[co];
        }
#pragma unroll
        for (int ni = 0; ni < 4; ++ni) {
            int h = h0 + 2 * wn + (ni >> 1);
            int w = (ni & 1) * 32 + el;
            float nz = nsv * noise[h * 64 + w];
#pragma unroll
            for (int rg = 0; rg < 16; ++rg) {
                int co = co0 + wm * 64 + mi * 32 + (rg & 3) + 8 * (rg >> 2) +
                         4 * hk;
                float v = acc[mi][ni][rg] * dm[rg] + nz + bs[rg];
                v = (v >= 0.f ? v : 0.2f * v) * LR;
                out[(((size_t)b * 512 + co) * 64 + h) * 64 + w] = v;
            }
        }
    }
}

// ---------------------------------------------------------------------------
extern "C" void kernel_launch(void* const* d_in, const int* in_sizes, int n_in,
                              void* d_out, int out_size, void* d_ws, size_t ws_size,
                              hipStream_t stream) {
    const float* x      = (const float*)d_in[0];
    const float* style  = (const float*)d_in[1];
    const float* noise  = (const float*)d_in[2];
    const float* weight = (const float*)d_in[3];
    const float* bias   = (const float*)d_in[4];
    const float* nstr   = (const float*)d_in[5];
    float* out = (float*)d_out;

    char* ws = (char*)d_ws;
    __hip_bfloat16* xs = (__hip_bfloat16*)ws;              // 35,684,352 B padded
    __hip_bfloat16* wb = (__hip_bfloat16*)(ws + 35684352); //  4,718,592 B
    float* demod = (float*)(ws + 35684352 + 4718592);      //     16,384 B

    k_prep<<<4104, 256, 0, stream>>>(x, style, weight, xs, wb, demod);
    k_conv<<<512, 256, 0, stream>>>(xs, wb, demod, noise, bias, nstr, out);
}